// Round 18
// baseline (219.481 us; speedup 1.0000x reference)
//
#include <hip/hip_runtime.h>
#include <hip/hip_bf16.h>

#define B_  2
#define T_  4096
#define C_  768
#define H_  12
#define D_  64
#define BT_ (B_*T_)   // 8192

typedef __attribute__((ext_vector_type(8))) short short8;
typedef __attribute__((ext_vector_type(4))) short short4b;
typedef __attribute__((ext_vector_type(4))) float f32x4;

union U32x2 { unsigned u[2]; short4b s4; };

__device__ __forceinline__ ushort f2bf(float f) {
  union { __hip_bfloat16 b; ushort u; } cv; cv.b = __float2bfloat16(f); return cv.u;
}
__device__ __forceinline__ float bf2f(ushort u) {
  unsigned x = ((unsigned)u) << 16; float f; __builtin_memcpy(&f, &x, 4); return f;
}
// compiler-friendly pack (clang fuses to v_cvt_pk_bf16_f32)
__device__ __forceinline__ unsigned pack2(float a, float b) {
  return (unsigned)f2bf(a) | ((unsigned)f2bf(b) << 16);
}

// async global->LDS, 16B per lane (dest = wave-uniform base + lane*16)
__device__ __forceinline__ void gl16(const ushort* g, ushort* l) {
  typedef const __attribute__((address_space(1))) unsigned GU;
  typedef __attribute__((address_space(3))) unsigned LU;
  __builtin_amdgcn_global_load_lds((GU*)g, (LU*)l, 16, 0, 0);
}

// 16x16x16 bf16 MFMA (K=16, A/B k-granule = lg*4+i) — builtin-name guarded.
__device__ __forceinline__ f32x4 mfma16(short4b a, short4b b, f32x4 c) {
#if __has_builtin(__builtin_amdgcn_mfma_f32_16x16x16bf16_1k)
  return __builtin_amdgcn_mfma_f32_16x16x16bf16_1k(a, b, c, 0, 0, 0);
#elif __has_builtin(__builtin_amdgcn_mfma_f32_16x16x16_bf16)
  return __builtin_amdgcn_mfma_f32_16x16x16_bf16(a, b, c, 0, 0, 0);
#else
  asm("v_mfma_f32_16x16x16_bf16 %0, %1, %2, %0" : "+v"(c) : "v"(a), "v"(b));
  return c;
#endif
}

// ---------------- elementwise converts ----------------
__global__ void k_f32_to_bf16(const float* __restrict__ in, ushort* __restrict__ out, int n4) {
  int i = blockIdx.x * blockDim.x + threadIdx.x;
  if (i >= n4) return;
  const float4 v = ((const float4*)in)[i];
  ushort4 o;
  o.x = f2bf(v.x); o.y = f2bf(v.y); o.z = f2bf(v.z); o.w = f2bf(v.w);
  ((ushort4*)out)[i] = o;
}

// all four weight matrices in one launch (blockIdx.y selects)
__global__ void k_w_to_bf16(const float* __restrict__ w0, const float* __restrict__ w1,
                            const float* __restrict__ w2, const float* __restrict__ w3,
                            ushort* __restrict__ o0, ushort* __restrict__ o1,
                            ushort* __restrict__ o2, ushort* __restrict__ o3, int n4) {
  int i = blockIdx.x * blockDim.x + threadIdx.x;
  if (i >= n4) return;
  const int sel = blockIdx.y;
  const float* in = sel == 0 ? w0 : (sel == 1 ? w1 : (sel == 2 ? w2 : w3));
  ushort* out = sel == 0 ? o0 : (sel == 1 ? o1 : (sel == 2 ? o2 : o3));
  const float4 v = ((const float4*)in)[i];
  ushort4 o;
  o.x = f2bf(v.x); o.y = f2bf(v.y); o.z = f2bf(v.z); o.w = f2bf(v.w);
  ((ushort4*)out)[i] = o;
}

__global__ void k_rope_tab(float* __restrict__ ctab, float* __restrict__ stab) {
  int i = blockIdx.x * blockDim.x + threadIdx.x;  // T_*32 threads
  int t = i >> 5, p = i & 31;
  float inv = 1.0f / powf(10000.0f, (2.0f * (float)p) / 64.0f);
  float a = (float)t * inv;
  ctab[i] = cosf(a); stab[i] = sinf(a);
}

// ---------------- QKV projection GEMM (RoPE fused into q/k epilogue) ----------
// global_load_lds width-16 staging, linear LDS [128][64] with rule-21 swizzle:
// src col8 = (l&7)^(row&7), frag-read slot = (kk*4+lg)^(row&7).
__global__ __launch_bounds__(256) void k_qkv_gemm(
    const ushort* __restrict__ xb, const ushort* __restrict__ wq,
    const ushort* __restrict__ wk, const ushort* __restrict__ wv,
    const float* __restrict__ bq, const float* __restrict__ bk, const float* __restrict__ bv,
    const float* __restrict__ ctab, const float* __restrict__ stab,
    ushort* __restrict__ qo, ushort* __restrict__ ko, ushort* __restrict__ vo) {
  __shared__ __align__(16) ushort As[128 * 64];
  __shared__ __align__(16) ushort Bs[128 * 64];
  const int tid = threadIdx.x, l = tid & 63, w = tid >> 6;
  const int lr = l & 15, lg = l >> 4;
  const int m0 = blockIdx.x * 128;
  const int n0g = blockIdx.y * 128;
  const int proj = n0g / 768;
  const int n0 = n0g % 768;
  const ushort* wsrc = proj == 0 ? wq : (proj == 1 ? wk : wv);
  const int wr = (w >> 1) * 64, wc = (w & 1) * 64;

  f32x4 acc[4][4];
  #pragma unroll
  for (int a = 0; a < 4; ++a)
    #pragma unroll
    for (int b = 0; b < 4; ++b) acc[a][b] = (f32x4){0.f, 0.f, 0.f, 0.f};

  // per-lane staging geometry (k0-invariant)
  const int srow = w * 32 + (l >> 3);
  const int scg = ((l & 7) ^ (srow & 7)) * 8;

  for (int k0 = 0; k0 < 768; k0 += 64) {
    #pragma unroll
    for (int i = 0; i < 4; ++i) {
      const int row = srow + i * 8;
      gl16(xb + (size_t)(m0 + row) * 768 + k0 + scg, &As[(w * 32 + i * 8) * 64]);
      gl16(wsrc + (size_t)(n0 + row) * 768 + k0 + scg, &Bs[(w * 32 + i * 8) * 64]);
    }
    __syncthreads();
    #pragma unroll
    for (int kk = 0; kk < 2; ++kk) {
      short8 af[4], bf[4];
      #pragma unroll
      for (int mi = 0; mi < 4; ++mi) {
        const int row = wr + mi * 16 + lr;
        af[mi] = *(const short8*)&As[row * 64 + (((kk * 4 + lg) ^ (row & 7)) * 8)];
      }
      #pragma unroll
      for (int ni = 0; ni < 4; ++ni) {
        const int row = wc + ni * 16 + lr;
        bf[ni] = *(const short8*)&Bs[row * 64 + (((kk * 4 + lg) ^ (row & 7)) * 8)];
      }
      #pragma unroll
      for (int mi = 0; mi < 4; ++mi)
        #pragma unroll
        for (int ni = 0; ni < 4; ++ni)
          acc[mi][ni] = __builtin_amdgcn_mfma_f32_16x16x32_bf16(af[mi], bf[ni], acc[mi][ni], 0, 0, 0);
    }
    __syncthreads();
  }

  const float* bias = proj == 0 ? bq : (proj == 1 ? bk : bv);
  if (proj == 2) {
    #pragma unroll
    for (int mi = 0; mi < 4; ++mi) {
      #pragma unroll
      for (int ni = 0; ni < 4; ++ni) {
        int colc = n0 + wc + ni * 16 + lr;
        float bb = bias[colc];
        int h = colc >> 6, d = colc & 63;
        int row0 = m0 + wr + mi * 16 + lg * 4;
        int b = row0 >> 12, t0 = row0 & (T_ - 1);
        ushort4 pk;
        pk.x = f2bf(acc[mi][ni][0] + bb);
        pk.y = f2bf(acc[mi][ni][1] + bb);
        pk.z = f2bf(acc[mi][ni][2] + bb);
        pk.w = f2bf(acc[mi][ni][3] + bb);
        *(ushort4*)(vo + (((size_t)b * H_ + h) * 64 + d) * T_ + t0) = pk;
      }
    }
  } else {
    // fused RoPE epilogue: d-pair partner lives in adjacent lane (lr^1).
    ushort* dst = proj == 0 ? qo : ko;
    const float qs = proj == 0 ? 0.18033688011112042f : 1.0f;   // log2(e)/8
    #pragma unroll
    for (int mi = 0; mi < 4; ++mi) {
      #pragma unroll
      for (int ni = 0; ni < 4; ++ni) {
        int colc = n0 + wc + ni * 16 + lr;
        float bb = bias[colc];
        int h = colc >> 6, d = colc & 63;
        const int pidx = d >> 1;
        const bool evn = (d & 1) == 0;
        #pragma unroll
        for (int j = 0; j < 4; ++j) {
          int row = m0 + wr + mi * 16 + lg * 4 + j;
          int b = row >> 12, t = row & (T_ - 1);
          float val = acc[mi][ni][j] + bb;          // biased (rope is post-bias)
          float prt = __shfl_xor(val, 1);           // partner d^1 (lane lr^1)
          float cc = ctab[(t << 5) + pidx];
          float ss = stab[(t << 5) + pidx];
          float ro = evn ? (val * cc - prt * ss) : (prt * ss + val * cc);
          dst[((((size_t)b * H_ + h) << 12) + t) * 64 + d] = f2bf(ro * qs);
        }
      }
    }
  }
}

// ---------------- output projection GEMM (f32 out) ----------------
// BM=64 x BN=128 -> grid (128, 6) = 768 = exactly 3/CU uniform. 24 KB LDS.
__global__ __launch_bounds__(256) void k_proj_gemm(
    const ushort* __restrict__ yb, const ushort* __restrict__ wp,
    const float* __restrict__ bp, float* __restrict__ out) {
  __shared__ __align__(16) ushort As[64 * 64];
  __shared__ __align__(16) ushort Bs[128 * 64];
  const int tid = threadIdx.x, l = tid & 63, w = tid >> 6;
  const int lr = l & 15, lg = l >> 4;
  const int m0 = blockIdx.x * 64;
  const int n0 = blockIdx.y * 128;
  const int wc = w * 32;

  f32x4 acc[4][2];
  #pragma unroll
  for (int a = 0; a < 4; ++a)
    #pragma unroll
    for (int b = 0; b < 2; ++b) acc[a][b] = (f32x4){0.f, 0.f, 0.f, 0.f};

  const int srowA = w * 16 + (l >> 3);
  const int scgA = ((l & 7) ^ (srowA & 7)) * 8;
  const int srowB = w * 32 + (l >> 3);
  const int scgB = ((l & 7) ^ (srowB & 7)) * 8;

  for (int k0 = 0; k0 < 768; k0 += 64) {
    #pragma unroll
    for (int i = 0; i < 2; ++i) {
      const int row = srowA + i * 8;
      gl16(yb + (size_t)(m0 + row) * 768 + k0 + scgA, &As[(w * 16 + i * 8) * 64]);
    }
    #pragma unroll
    for (int i = 0; i < 4; ++i) {
      const int row = srowB + i * 8;
      gl16(wp + (size_t)(n0 + row) * 768 + k0 + scgB, &Bs[(w * 32 + i * 8) * 64]);
    }
    __syncthreads();
    #pragma unroll
    for (int kk = 0; kk < 2; ++kk) {
      short8 af[4], bf[2];
      #pragma unroll
      for (int mi = 0; mi < 4; ++mi) {
        const int row = mi * 16 + lr;
        af[mi] = *(const short8*)&As[row * 64 + (((kk * 4 + lg) ^ (row & 7)) * 8)];
      }
      #pragma unroll
      for (int ni = 0; ni < 2; ++ni) {
        const int row = wc + ni * 16 + lr;
        bf[ni] = *(const short8*)&Bs[row * 64 + (((kk * 4 + lg) ^ (row & 7)) * 8)];
      }
      #pragma unroll
      for (int mi = 0; mi < 4; ++mi)
        #pragma unroll
        for (int ni = 0; ni < 2; ++ni)
          acc[mi][ni] = __builtin_amdgcn_mfma_f32_16x16x32_bf16(af[mi], bf[ni], acc[mi][ni], 0, 0, 0);
    }
    __syncthreads();
  }

  #pragma unroll
  for (int mi = 0; mi < 4; ++mi)
    #pragma unroll
    for (int ni = 0; ni < 2; ++ni) {
      int col = n0 + wc + ni * 16 + lr;
      float bb = bp[col];
      #pragma unroll
      for (int j = 0; j < 4; ++j) {
        int row = m0 + mi * 16 + lg * 4 + j;
        out[(size_t)row * 768 + col] = acc[mi][ni][j] + bb;
      }
    }
}

// ---------------- causal flash attention: UNIFORM 65-iter blocks --------------
// R17 structure. NEW vs R17: K/V staging via global_load_lds width-16 (issued
// right after the top barrier into buf^1, drained by the next barrier's vmcnt).
// Rule-21: LDS linear, SOURCE col pre-swizzled by (l&7)^((l>>3)&7) — produces
// the identical swizzled layout, so all read offsets are unchanged.
__global__ __launch_bounds__(256) void k_attn(
    const ushort* __restrict__ q, const ushort* __restrict__ k,
    const ushort* __restrict__ vt, ushort* __restrict__ y) {
  __shared__ __align__(16) ushort Ks[2][64 * 64];
  __shared__ __align__(16) ushort Vs[2][64 * 64];
  const int tid = threadIdx.x, l = tid & 63, w = tid >> 6;
  const int lr = l & 15, lg = l >> 4;
  const int p = blockIdx.x & 31;
  const int bh = blockIdx.x >> 5;
  const size_t kpl = (size_t)bh * T_ * 64;
  const size_t vpl = (size_t)bh * 64 * T_;
  const int b = bh / H_, h = bh % H_;
  const short4b ones4 = { (short)0x3F80, (short)0x3F80, (short)0x3F80, (short)0x3F80 };

  // lane-constant pre-swizzled source col offset (row&7 == (l>>3)&7 for 8-row issues)
  const int sc8 = ((l & 7) ^ ((l >> 3) & 7)) * 8;

  #pragma unroll 1
  for (int ph = 0; ph < 2; ++ph) {
    const int t = ph == 0 ? p : 63 - p;
    const int nt = t + 1;
    const int qrow = t * 64 + w * 16 + lr;

    // Q fragments (B operand of S^T = K·Q: col=q=lane&15, k-rows = d)
    short8 qf[2];
    #pragma unroll
    for (int kk = 0; kk < 2; ++kk)
      qf[kk] = *(const short8*)(q + kpl + (size_t)qrow * 64 + kk * 32 + lg * 8);

    f32x4 o[4];
    f32x4 lsa = (f32x4){0.f, 0.f, 0.f, 0.f};   // MFMA-accumulated denominator
    float mx = 0.0f;   // running shift (grows only via exponent rescale)
    #pragma unroll
    for (int c = 0; c < 4; ++c) o[c] = (f32x4){0.f, 0.f, 0.f, 0.f};

    // strength-reduced pre-swizzled staging pointers (tile 0)
    const ushort* kg0 = k + kpl + (size_t)(w * 16 + (l >> 3)) * 64 + sc8;
    const ushort* kg1 = kg0 + 8 * 64;
    const ushort* vg0 = vt + vpl + (size_t)(w * 16 + (l >> 3)) * T_ + sc8;
    const ushort* vg1 = vg0 + 8 * T_;

    __syncthreads();   // previous phase's LDS reads complete before re-staging
    // prologue: stage tile 0 into buf 0 (async DMA; drained at loop-top barrier)
    gl16(kg0, &Ks[0][(w * 16) * 64]);
    gl16(kg1, &Ks[0][(w * 16 + 8) * 64]);
    gl16(vg0, &Vs[0][(w * 16) * 64]);
    gl16(vg1, &Vs[0][(w * 16 + 8) * 64]);
    kg0 += 4096; kg1 += 4096; vg0 += 64; vg1 += 64;

    int buf = 0;
    for (int kt = 0; kt < nt; ++kt) {
      __syncthreads();   // drains in-flight gl16 (vmcnt before barrier)
      // issue next tile's DMA into buf^1 (free since last iteration)
      if (kt + 1 < nt) {
        ushort* kd = &Ks[buf ^ 1][0];
        ushort* vd = &Vs[buf ^ 1][0];
        gl16(kg0, kd + (w * 16) * 64);
        gl16(kg1, kd + (w * 16 + 8) * 64);
        gl16(vg0, vd + (w * 16) * 64);
        gl16(vg1, vd + (w * 16 + 8) * 64);
        kg0 += 4096; kg1 += 4096; vg0 += 64; vg1 += 64;
      }

      // ---- S^T = K·Q - mx (shift folded into MFMA C-init) ----
      const f32x4 zinit = (f32x4){-mx, -mx, -mx, -mx};
      f32x4 sT[4];
      __builtin_amdgcn_s_setprio(1);
      #pragma unroll
      for (int c = 0; c < 4; ++c) {
        short8 kf0 = *(const short8*)&Ks[buf][(c * 16 + lr) * 64 + ((lg) ^ (lr & 7)) * 8];
        short8 kf1 = *(const short8*)&Ks[buf][(c * 16 + lr) * 64 + ((4 + lg) ^ (lr & 7)) * 8];
        f32x4 z = zinit;
        z = __builtin_amdgcn_mfma_f32_16x16x32_bf16(kf0, qf[0], z, 0, 0, 0);
        z = __builtin_amdgcn_mfma_f32_16x16x32_bf16(kf1, qf[1], z, 0, 0, 0);
        sT[c] = z;
      }
      __builtin_amdgcn_s_setprio(0);

      // ---- causal mask on diagonal tile (S^T row=key, col=q) ----
      if (kt == t) {
        #pragma unroll
        for (int c = 0; c < 4; ++c)
          #pragma unroll
          for (int jj = 0; jj < 4; ++jj)
            if (kt * 64 + c * 16 + lg * 4 + jj > qrow) sT[c][jj] = -1e30f;
      }

      // ---- exponent-triggered rescale (no max tracking, no cross-lane) ----
      const unsigned lbits = __builtin_bit_cast(unsigned, lsa[0]);
      if (lbits > 0x4B800000u) {            // lsa > 2^24 (uint cmp, positive f32)
        const int e = (int)((lbits >> 23) & 0xFF) - 127;
        const float g = (float)e;
        const float corr = __builtin_bit_cast(float, (unsigned)((127 - e) << 23)); // 2^-e
        mx += g;
        lsa *= corr;
        #pragma unroll
        for (int c = 0; c < 4; ++c) o[c] *= corr;
        #pragma unroll
        for (int c = 0; c < 4; ++c)
          #pragma unroll
          for (int jj = 0; jj < 4; ++jj) sT[c][jj] -= g;
      }
      // common path: p = exp2(sT) directly — no max, no subtraction, no shfl
      U32x2 pb[4];
      #pragma unroll
      for (int c = 0; c < 4; ++c) {
        float p0 = exp2f(sT[c][0]);
        float p1 = exp2f(sT[c][1]);
        float p2 = exp2f(sT[c][2]);
        float p3 = exp2f(sT[c][3]);
        pb[c].u[0] = pack2(p0, p1); pb[c].u[1] = pack2(p2, p3);
      }

      // ---- O^T += V^T·P^T and lsa += 1^T·P^T via 16x16x16 (P in-lane) ----
      __builtin_amdgcn_s_setprio(1);
      #pragma unroll
      for (int ks = 0; ks < 4; ++ks) {
        lsa = mfma16(ones4, pb[ks].s4, lsa);    // denominator on the MFMA pipe
        #pragma unroll
        for (int c = 0; c < 4; ++c) {
          const int row = c * 16 + lr;
          const int sl = (2 * ks + (lg >> 1)) ^ (row & 7);
          short4b va = *(const short4b*)&Vs[buf][row * 64 + sl * 8 + (lg & 1) * 4];
          o[c] = mfma16(va, pb[ks].s4, o[c]);
        }
      }
      __builtin_amdgcn_s_setprio(0);

      buf ^= 1;
    }

    // phase epilogue: normalize (lane-local; lsa rows all equal) + write y
    const float linv = 1.0f / lsa[0];
    const size_t base = ((size_t)b * T_ + qrow) * C_ + h * 64;
    #pragma unroll
    for (int c = 0; c < 4; ++c) {
      ushort4 pk;
      pk.x = f2bf(o[c][0] * linv);
      pk.y = f2bf(o[c][1] * linv);
      pk.z = f2bf(o[c][2] * linv);
      pk.w = f2bf(o[c][3] * linv);
      *(ushort4*)(y + base + c * 16 + lg * 4) = pk;
    }
  }
}

extern "C" void kernel_launch(void* const* d_in, const int* in_sizes, int n_in,
                              void* d_out, int out_size, void* d_ws, size_t ws_size,
                              hipStream_t stream) {
  const float* x  = (const float*)d_in[0];
  const float* Wq = (const float*)d_in[1];
  const float* bq = (const float*)d_in[2];
  const float* Wk = (const float*)d_in[3];
  const float* bk = (const float*)d_in[4];
  const float* Wv = (const float*)d_in[5];
  const float* bv = (const float*)d_in[6];
  const float* Wp = (const float*)d_in[7];
  const float* bp = (const float*)d_in[8];
  float* out = (float*)d_out;

  // ws: exact R3-proven footprint (~69 MB)
  char* p = (char*)d_ws;
  auto alloc = [&](size_t bytes) { char* r = p; p += (bytes + 255) & ~255ULL; return r; };
  ushort* xb  = (ushort*)alloc((size_t)BT_ * C_ * 2);
  ushort* wqb = (ushort*)alloc((size_t)C_ * C_ * 2);
  ushort* wkb = (ushort*)alloc((size_t)C_ * C_ * 2);
  ushort* wvb = (ushort*)alloc((size_t)C_ * C_ * 2);
  ushort* wpb = (ushort*)alloc((size_t)C_ * C_ * 2);
  ushort* qb  = (ushort*)alloc((size_t)BT_ * C_ * 2);
  ushort* kb  = (ushort*)alloc((size_t)BT_ * C_ * 2);
  ushort* vtb = (ushort*)alloc((size_t)BT_ * C_ * 2);   // V^T [B,H,64,T]
  ushort* yb  = (ushort*)alloc((size_t)BT_ * C_ * 2);
  float* ctab = (float*)alloc((size_t)T_ * 32 * 4);
  float* stab = (float*)alloc((size_t)T_ * 32 * 4);

  k_f32_to_bf16<<<(BT_ * C_ / 4 + 255) / 256, 256, 0, stream>>>(x, xb, BT_ * C_ / 4);
  k_w_to_bf16<<<dim3((C_ * C_ / 4 + 255) / 256, 4), 256, 0, stream>>>(
      Wq, Wk, Wv, Wp, wqb, wkb, wvb, wpb, C_ * C_ / 4);
  k_rope_tab<<<T_ * 32 / 256, 256, 0, stream>>>(ctab, stab);

  // QKV projection with fused RoPE (q scaled by log2(e)/8 for exp2-domain softmax)
  k_qkv_gemm<<<dim3(BT_ / 128, 2304 / 128), 256, 0, stream>>>(
      xb, wqb, wkb, wvb, bq, bk, bv, ctab, stab, qb, kb, vtb);

  k_attn<<<dim3(768), 256, 0, stream>>>(qb, kb, vtb, yb);

  k_proj_gemm<<<dim3(BT_ / 64, C_ / 128), 256, 0, stream>>>(yb, wpb, bp, out);
}

// Round 19
// 201.290 us; speedup vs baseline: 1.0904x; 1.0904x over previous
//
#include <hip/hip_runtime.h>
#include <hip/hip_bf16.h>

#define B_  2
#define T_  4096
#define C_  768
#define H_  12
#define D_  64
#define BT_ (B_*T_)   // 8192

typedef __attribute__((ext_vector_type(8))) short short8;
typedef __attribute__((ext_vector_type(4))) short short4b;
typedef __attribute__((ext_vector_type(4))) float f32x4;

union U32x2 { unsigned u[2]; short4b s4; };

__device__ __forceinline__ ushort f2bf(float f) {
  union { __hip_bfloat16 b; ushort u; } cv; cv.b = __float2bfloat16(f); return cv.u;
}
__device__ __forceinline__ float bf2f(ushort u) {
  unsigned x = ((unsigned)u) << 16; float f; __builtin_memcpy(&f, &x, 4); return f;
}
// compiler-friendly pack (clang fuses to v_cvt_pk_bf16_f32)
__device__ __forceinline__ unsigned pack2(float a, float b) {
  return (unsigned)f2bf(a) | ((unsigned)f2bf(b) << 16);
}

// async global->LDS, 16B per lane (dest = wave-uniform base + lane*16)
__device__ __forceinline__ void gl16(const ushort* g, ushort* l) {
  typedef const __attribute__((address_space(1))) unsigned GU;
  typedef __attribute__((address_space(3))) unsigned LU;
  __builtin_amdgcn_global_load_lds((GU*)g, (LU*)l, 16, 0, 0);
}

// 16x16x16 bf16 MFMA (K=16, A/B k-granule = lg*4+i) — builtin-name guarded.
__device__ __forceinline__ f32x4 mfma16(short4b a, short4b b, f32x4 c) {
#if __has_builtin(__builtin_amdgcn_mfma_f32_16x16x16bf16_1k)
  return __builtin_amdgcn_mfma_f32_16x16x16bf16_1k(a, b, c, 0, 0, 0);
#elif __has_builtin(__builtin_amdgcn_mfma_f32_16x16x16_bf16)
  return __builtin_amdgcn_mfma_f32_16x16x16_bf16(a, b, c, 0, 0, 0);
#else
  asm("v_mfma_f32_16x16x16_bf16 %0, %1, %2, %0" : "+v"(c) : "v"(a), "v"(b));
  return c;
#endif
}

// ---------------- fused prep: x-convert | 4 weight-converts | rope tables -----
// flat bid partition: [0,6144) x | [6144,8448) weights | [8448,8960) rope.
__global__ void k_prep(const float* __restrict__ x,
                       const float* __restrict__ w0, const float* __restrict__ w1,
                       const float* __restrict__ w2, const float* __restrict__ w3,
                       ushort* __restrict__ xb,
                       ushort* __restrict__ o0, ushort* __restrict__ o1,
                       ushort* __restrict__ o2, ushort* __restrict__ o3,
                       float* __restrict__ ctab, float* __restrict__ stab) {
  const int bid = blockIdx.x;
  if (bid < 6144) {                         // x: BT_*C_/4 = 1,572,864 float4
    const int i = bid * 256 + threadIdx.x;
    const float4 v = ((const float4*)x)[i];
    ushort4 o;
    o.x = f2bf(v.x); o.y = f2bf(v.y); o.z = f2bf(v.z); o.w = f2bf(v.w);
    ((ushort4*)xb)[i] = o;
  } else if (bid < 8448) {                  // weights: 4 x 576 blocks
    const int r = bid - 6144;
    const int sel = r / 576;
    const int i = (r % 576) * 256 + threadIdx.x;
    const float* in = sel == 0 ? w0 : (sel == 1 ? w1 : (sel == 2 ? w2 : w3));
    ushort* out = sel == 0 ? o0 : (sel == 1 ? o1 : (sel == 2 ? o2 : o3));
    const float4 v = ((const float4*)in)[i];
    ushort4 o;
    o.x = f2bf(v.x); o.y = f2bf(v.y); o.z = f2bf(v.z); o.w = f2bf(v.w);
    ((ushort4*)out)[i] = o;
  } else {                                  // rope tables: T_*32 = 131,072
    const int i = (bid - 8448) * 256 + threadIdx.x;
    const int t = i >> 5, p = i & 31;
    float inv = 1.0f / powf(10000.0f, (2.0f * (float)p) / 64.0f);
    float a = (float)t * inv;
    ctab[i] = cosf(a); stab[i] = sinf(a);
  }
}

// ---------------- QKV projection GEMM (RoPE fused into q/k epilogue) ----------
// global_load_lds width-16 staging, linear LDS [128][64] with rule-21 swizzle:
// src col8 = (l&7)^(row&7), frag-read slot = (kk*4+lg)^(row&7).
__global__ __launch_bounds__(256) void k_qkv_gemm(
    const ushort* __restrict__ xb, const ushort* __restrict__ wq,
    const ushort* __restrict__ wk, const ushort* __restrict__ wv,
    const float* __restrict__ bq, const float* __restrict__ bk, const float* __restrict__ bv,
    const float* __restrict__ ctab, const float* __restrict__ stab,
    ushort* __restrict__ qo, ushort* __restrict__ ko, ushort* __restrict__ vo) {
  __shared__ __align__(16) ushort As[128 * 64];
  __shared__ __align__(16) ushort Bs[128 * 64];
  const int tid = threadIdx.x, l = tid & 63, w = tid >> 6;
  const int lr = l & 15, lg = l >> 4;
  const int m0 = blockIdx.x * 128;
  const int n0g = blockIdx.y * 128;
  const int proj = n0g / 768;
  const int n0 = n0g % 768;
  const ushort* wsrc = proj == 0 ? wq : (proj == 1 ? wk : wv);
  const int wr = (w >> 1) * 64, wc = (w & 1) * 64;

  f32x4 acc[4][4];
  #pragma unroll
  for (int a = 0; a < 4; ++a)
    #pragma unroll
    for (int b = 0; b < 4; ++b) acc[a][b] = (f32x4){0.f, 0.f, 0.f, 0.f};

  // per-lane staging geometry (k0-invariant)
  const int srow = w * 32 + (l >> 3);
  const int scg = ((l & 7) ^ (srow & 7)) * 8;

  for (int k0 = 0; k0 < 768; k0 += 64) {
    #pragma unroll
    for (int i = 0; i < 4; ++i) {
      const int row = srow + i * 8;
      gl16(xb + (size_t)(m0 + row) * 768 + k0 + scg, &As[(w * 32 + i * 8) * 64]);
      gl16(wsrc + (size_t)(n0 + row) * 768 + k0 + scg, &Bs[(w * 32 + i * 8) * 64]);
    }
    __syncthreads();
    #pragma unroll
    for (int kk = 0; kk < 2; ++kk) {
      short8 af[4], bf[4];
      #pragma unroll
      for (int mi = 0; mi < 4; ++mi) {
        const int row = wr + mi * 16 + lr;
        af[mi] = *(const short8*)&As[row * 64 + (((kk * 4 + lg) ^ (row & 7)) * 8)];
      }
      #pragma unroll
      for (int ni = 0; ni < 4; ++ni) {
        const int row = wc + ni * 16 + lr;
        bf[ni] = *(const short8*)&Bs[row * 64 + (((kk * 4 + lg) ^ (row & 7)) * 8)];
      }
      #pragma unroll
      for (int mi = 0; mi < 4; ++mi)
        #pragma unroll
        for (int ni = 0; ni < 4; ++ni)
          acc[mi][ni] = __builtin_amdgcn_mfma_f32_16x16x32_bf16(af[mi], bf[ni], acc[mi][ni], 0, 0, 0);
    }
    __syncthreads();
  }

  const float* bias = proj == 0 ? bq : (proj == 1 ? bk : bv);
  if (proj == 2) {
    #pragma unroll
    for (int mi = 0; mi < 4; ++mi) {
      #pragma unroll
      for (int ni = 0; ni < 4; ++ni) {
        int colc = n0 + wc + ni * 16 + lr;
        float bb = bias[colc];
        int h = colc >> 6, d = colc & 63;
        int row0 = m0 + wr + mi * 16 + lg * 4;
        int b = row0 >> 12, t0 = row0 & (T_ - 1);
        ushort4 pk;
        pk.x = f2bf(acc[mi][ni][0] + bb);
        pk.y = f2bf(acc[mi][ni][1] + bb);
        pk.z = f2bf(acc[mi][ni][2] + bb);
        pk.w = f2bf(acc[mi][ni][3] + bb);
        *(ushort4*)(vo + (((size_t)b * H_ + h) * 64 + d) * T_ + t0) = pk;
      }
    }
  } else {
    // fused RoPE epilogue: d-pair partner lives in adjacent lane (lr^1).
    ushort* dst = proj == 0 ? qo : ko;
    const float qs = proj == 0 ? 0.18033688011112042f : 1.0f;   // log2(e)/8
    #pragma unroll
    for (int mi = 0; mi < 4; ++mi) {
      #pragma unroll
      for (int ni = 0; ni < 4; ++ni) {
        int colc = n0 + wc + ni * 16 + lr;
        float bb = bias[colc];
        int h = colc >> 6, d = colc & 63;
        const int pidx = d >> 1;
        const bool evn = (d & 1) == 0;
        #pragma unroll
        for (int j = 0; j < 4; ++j) {
          int row = m0 + wr + mi * 16 + lg * 4 + j;
          int b = row >> 12, t = row & (T_ - 1);
          float val = acc[mi][ni][j] + bb;          // biased (rope is post-bias)
          float prt = __shfl_xor(val, 1);           // partner d^1 (lane lr^1)
          float cc = ctab[(t << 5) + pidx];
          float ss = stab[(t << 5) + pidx];
          float ro = evn ? (val * cc - prt * ss) : (prt * ss + val * cc);
          dst[((((size_t)b * H_ + h) << 12) + t) * 64 + d] = f2bf(ro * qs);
        }
      }
    }
  }
}

// ---------------- output projection GEMM (f32 out) ----------------
// BM=64 x BN=128 -> grid (128, 6) = 768 = exactly 3/CU uniform. 24 KB LDS.
__global__ __launch_bounds__(256) void k_proj_gemm(
    const ushort* __restrict__ yb, const ushort* __restrict__ wp,
    const float* __restrict__ bp, float* __restrict__ out) {
  __shared__ __align__(16) ushort As[64 * 64];
  __shared__ __align__(16) ushort Bs[128 * 64];
  const int tid = threadIdx.x, l = tid & 63, w = tid >> 6;
  const int lr = l & 15, lg = l >> 4;
  const int m0 = blockIdx.x * 64;
  const int n0 = blockIdx.y * 128;
  const int wc = w * 32;

  f32x4 acc[4][2];
  #pragma unroll
  for (int a = 0; a < 4; ++a)
    #pragma unroll
    for (int b = 0; b < 2; ++b) acc[a][b] = (f32x4){0.f, 0.f, 0.f, 0.f};

  const int srowA = w * 16 + (l >> 3);
  const int scgA = ((l & 7) ^ (srowA & 7)) * 8;
  const int srowB = w * 32 + (l >> 3);
  const int scgB = ((l & 7) ^ (srowB & 7)) * 8;

  for (int k0 = 0; k0 < 768; k0 += 64) {
    #pragma unroll
    for (int i = 0; i < 2; ++i) {
      const int row = srowA + i * 8;
      gl16(yb + (size_t)(m0 + row) * 768 + k0 + scgA, &As[(w * 16 + i * 8) * 64]);
    }
    #pragma unroll
    for (int i = 0; i < 4; ++i) {
      const int row = srowB + i * 8;
      gl16(wp + (size_t)(n0 + row) * 768 + k0 + scgB, &Bs[(w * 32 + i * 8) * 64]);
    }
    __syncthreads();
    #pragma unroll
    for (int kk = 0; kk < 2; ++kk) {
      short8 af[4], bf[2];
      #pragma unroll
      for (int mi = 0; mi < 4; ++mi) {
        const int row = mi * 16 + lr;
        af[mi] = *(const short8*)&As[row * 64 + (((kk * 4 + lg) ^ (row & 7)) * 8)];
      }
      #pragma unroll
      for (int ni = 0; ni < 2; ++ni) {
        const int row = wc + ni * 16 + lr;
        bf[ni] = *(const short8*)&Bs[row * 64 + (((kk * 4 + lg) ^ (row & 7)) * 8)];
      }
      #pragma unroll
      for (int mi = 0; mi < 4; ++mi)
        #pragma unroll
        for (int ni = 0; ni < 2; ++ni)
          acc[mi][ni] = __builtin_amdgcn_mfma_f32_16x16x32_bf16(af[mi], bf[ni], acc[mi][ni], 0, 0, 0);
    }
    __syncthreads();
  }

  #pragma unroll
  for (int mi = 0; mi < 4; ++mi)
    #pragma unroll
    for (int ni = 0; ni < 2; ++ni) {
      int col = n0 + wc + ni * 16 + lr;
      float bb = bp[col];
      #pragma unroll
      for (int j = 0; j < 4; ++j) {
        int row = m0 + mi * 16 + lg * 4 + j;
        out[(size_t)row * 768 + col] = acc[mi][ni][j] + bb;
      }
    }
}

// ---------------- causal flash attention: UNIFORM 65-iter blocks --------------
// R17-proven optimum restored VERBATIM (131 us): reg round-trip async-split
// staging (T14; gl16-DMA variant regressed — barrier vmcnt drain serializes),
// exponent-triggered rescale (no max tracking), MFMA denominator, setprio.
__global__ __launch_bounds__(256) void k_attn(
    const ushort* __restrict__ q, const ushort* __restrict__ k,
    const ushort* __restrict__ vt, ushort* __restrict__ y) {
  __shared__ __align__(16) ushort Ks[2][64 * 64];
  __shared__ __align__(16) ushort Vs[2][64 * 64];
  const int tid = threadIdx.x, l = tid & 63, w = tid >> 6;
  const int lr = l & 15, lg = l >> 4;
  const int p = blockIdx.x & 31;
  const int bh = blockIdx.x >> 5;
  const size_t kpl = (size_t)bh * T_ * 64;
  const size_t vpl = (size_t)bh * 64 * T_;
  const int b = bh / H_, h = bh % H_;
  const short4b ones4 = { (short)0x3F80, (short)0x3F80, (short)0x3F80, (short)0x3F80 };

  #pragma unroll 1
  for (int ph = 0; ph < 2; ++ph) {
    const int t = ph == 0 ? p : 63 - p;
    const int nt = t + 1;
    const int qrow = t * 64 + w * 16 + lr;

    // Q fragments (B operand of S^T = K·Q: col=q=lane&15, k-rows = d)
    short8 qf[2];
    #pragma unroll
    for (int kk = 0; kk < 2; ++kk)
      qf[kk] = *(const short8*)(q + kpl + (size_t)qrow * 64 + kk * 32 + lg * 8);

    f32x4 o[4];
    f32x4 lsa = (f32x4){0.f, 0.f, 0.f, 0.f};   // MFMA-accumulated denominator
    float mx = 0.0f;   // running shift (grows only via exponent rescale)
    #pragma unroll
    for (int c = 0; c < 4; ++c) o[c] = (f32x4){0.f, 0.f, 0.f, 0.f};

    __syncthreads();   // previous phase's LDS reads complete before re-staging
    // prologue: stage tile 0 into buf 0 (XOR-swizzled 16B slots)
    {
      #pragma unroll
      for (int i2 = 0; i2 < 2; ++i2) {
        const int r = w * 16 + i2 * 8 + (l >> 3);
        const int sl = (l & 7) ^ (r & 7);
        short8 s0 = *(const short8*)(k + kpl + (size_t)r * 64 + (l & 7) * 8);
        short8 v0 = *(const short8*)(vt + vpl + (size_t)r * T_ + (l & 7) * 8);
        *(short8*)&Ks[0][r * 64 + sl * 8] = s0;
        *(short8*)&Vs[0][r * 64 + sl * 8] = v0;
      }
    }

    int buf = 0;
    for (int kt = 0; kt < nt; ++kt) {
      __syncthreads();
      // async-split staging: issue next tile's global loads before compute
      short8 sk[2], sv[2];
      const bool pre = (kt + 1 < nt);
      if (pre) {
        #pragma unroll
        for (int i2 = 0; i2 < 2; ++i2) {
          const int r = w * 16 + i2 * 8 + (l >> 3);
          sk[i2] = *(const short8*)(k + kpl + (size_t)((kt + 1) * 64 + r) * 64 + (l & 7) * 8);
          sv[i2] = *(const short8*)(vt + vpl + (size_t)r * T_ + (kt + 1) * 64 + (l & 7) * 8);
        }
      }

      // ---- S^T = K·Q - mx (shift folded into MFMA C-init) ----
      const f32x4 zinit = (f32x4){-mx, -mx, -mx, -mx};
      f32x4 sT[4];
      __builtin_amdgcn_s_setprio(1);
      #pragma unroll
      for (int c = 0; c < 4; ++c) {
        short8 kf0 = *(const short8*)&Ks[buf][(c * 16 + lr) * 64 + ((lg) ^ (lr & 7)) * 8];
        short8 kf1 = *(const short8*)&Ks[buf][(c * 16 + lr) * 64 + ((4 + lg) ^ (lr & 7)) * 8];
        f32x4 z = zinit;
        z = __builtin_amdgcn_mfma_f32_16x16x32_bf16(kf0, qf[0], z, 0, 0, 0);
        z = __builtin_amdgcn_mfma_f32_16x16x32_bf16(kf1, qf[1], z, 0, 0, 0);
        sT[c] = z;
      }
      __builtin_amdgcn_s_setprio(0);

      // ---- causal mask on diagonal tile (S^T row=key, col=q) ----
      if (kt == t) {
        #pragma unroll
        for (int c = 0; c < 4; ++c)
          #pragma unroll
          for (int jj = 0; jj < 4; ++jj)
            if (kt * 64 + c * 16 + lg * 4 + jj > qrow) sT[c][jj] = -1e30f;
      }

      // ---- exponent-triggered rescale (no max tracking, no cross-lane) ----
      const unsigned lbits = __builtin_bit_cast(unsigned, lsa[0]);
      if (lbits > 0x4B800000u) {            // lsa > 2^24 (uint cmp, positive f32)
        const int e = (int)((lbits >> 23) & 0xFF) - 127;
        const float g = (float)e;
        const float corr = __builtin_bit_cast(float, (unsigned)((127 - e) << 23)); // 2^-e
        mx += g;
        lsa *= corr;
        #pragma unroll
        for (int c = 0; c < 4; ++c) o[c] *= corr;
        #pragma unroll
        for (int c = 0; c < 4; ++c)
          #pragma unroll
          for (int jj = 0; jj < 4; ++jj) sT[c][jj] -= g;
      }
      // common path: p = exp2(sT) directly — no max, no subtraction, no shfl
      U32x2 pb[4];
      #pragma unroll
      for (int c = 0; c < 4; ++c) {
        float p0 = exp2f(sT[c][0]);
        float p1 = exp2f(sT[c][1]);
        float p2 = exp2f(sT[c][2]);
        float p3 = exp2f(sT[c][3]);
        pb[c].u[0] = pack2(p0, p1); pb[c].u[1] = pack2(p2, p3);
      }

      // ---- O^T += V^T·P^T and lsa += 1^T·P^T via 16x16x16 (P in-lane) ----
      __builtin_amdgcn_s_setprio(1);
      #pragma unroll
      for (int ks = 0; ks < 4; ++ks) {
        lsa = mfma16(ones4, pb[ks].s4, lsa);    // denominator on the MFMA pipe
        #pragma unroll
        for (int c = 0; c < 4; ++c) {
          const int row = c * 16 + lr;
          const int sl = (2 * ks + (lg >> 1)) ^ (row & 7);
          short4b va = *(const short4b*)&Vs[buf][row * 64 + sl * 8 + (lg & 1) * 4];
          o[c] = mfma16(va, pb[ks].s4, o[c]);
        }
      }
      __builtin_amdgcn_s_setprio(0);

      if (pre) {
        #pragma unroll
        for (int i2 = 0; i2 < 2; ++i2) {
          const int r = w * 16 + i2 * 8 + (l >> 3);
          const int sl = (l & 7) ^ (r & 7);
          *(short8*)&Ks[buf ^ 1][r * 64 + sl * 8] = sk[i2];
          *(short8*)&Vs[buf ^ 1][r * 64 + sl * 8] = sv[i2];
        }
      }
      buf ^= 1;
    }

    // phase epilogue: normalize (lane-local; lsa rows all equal) + write y
    const float linv = 1.0f / lsa[0];
    const size_t base = ((size_t)b * T_ + qrow) * C_ + h * 64;
    #pragma unroll
    for (int c = 0; c < 4; ++c) {
      ushort4 pk;
      pk.x = f2bf(o[c][0] * linv);
      pk.y = f2bf(o[c][1] * linv);
      pk.z = f2bf(o[c][2] * linv);
      pk.w = f2bf(o[c][3] * linv);
      *(ushort4*)(y + base + c * 16 + lg * 4) = pk;
    }
  }
}

extern "C" void kernel_launch(void* const* d_in, const int* in_sizes, int n_in,
                              void* d_out, int out_size, void* d_ws, size_t ws_size,
                              hipStream_t stream) {
  const float* x  = (const float*)d_in[0];
  const float* Wq = (const float*)d_in[1];
  const float* bq = (const float*)d_in[2];
  const float* Wk = (const float*)d_in[3];
  const float* bk = (const float*)d_in[4];
  const float* Wv = (const float*)d_in[5];
  const float* bv = (const float*)d_in[6];
  const float* Wp = (const float*)d_in[7];
  const float* bp = (const float*)d_in[8];
  float* out = (float*)d_out;

  // ws: exact R3-proven footprint (~69 MB)
  char* p = (char*)d_ws;
  auto alloc = [&](size_t bytes) { char* r = p; p += (bytes + 255) & ~255ULL; return r; };
  ushort* xb  = (ushort*)alloc((size_t)BT_ * C_ * 2);
  ushort* wqb = (ushort*)alloc((size_t)C_ * C_ * 2);
  ushort* wkb = (ushort*)alloc((size_t)C_ * C_ * 2);
  ushort* wvb = (ushort*)alloc((size_t)C_ * C_ * 2);
  ushort* wpb = (ushort*)alloc((size_t)C_ * C_ * 2);
  ushort* qb  = (ushort*)alloc((size_t)BT_ * C_ * 2);
  ushort* kb  = (ushort*)alloc((size_t)BT_ * C_ * 2);
  ushort* vtb = (ushort*)alloc((size_t)BT_ * C_ * 2);   // V^T [B,H,64,T]
  ushort* yb  = (ushort*)alloc((size_t)BT_ * C_ * 2);
  float* ctab = (float*)alloc((size_t)T_ * 32 * 4);
  float* stab = (float*)alloc((size_t)T_ * 32 * 4);

  // fused prep: x-convert + 4 weight converts + rope tables in ONE launch
  k_prep<<<dim3(8960), 256, 0, stream>>>(x, Wq, Wk, Wv, Wp,
                                         xb, wqb, wkb, wvb, wpb, ctab, stab);

  // QKV projection with fused RoPE (q scaled by log2(e)/8 for exp2-domain softmax)
  k_qkv_gemm<<<dim3(BT_ / 128, 2304 / 128), 256, 0, stream>>>(
      xb, wqb, wkb, wvb, bq, bk, bv, ctab, stab, qb, kb, vtb);

  k_attn<<<dim3(768), 256, 0, stream>>>(qb, kb, vtb, yb);

  k_proj_gemm<<<dim3(BT_ / 64, C_ / 128), 256, 0, stream>>>(yb, wpb, bp, out);
}

// Round 20
// 189.535 us; speedup vs baseline: 1.1580x; 1.0620x over previous
//
#include <hip/hip_runtime.h>
#include <hip/hip_bf16.h>

#define B_  2
#define T_  4096
#define C_  768
#define H_  12
#define D_  64
#define BT_ (B_*T_)   // 8192

typedef __attribute__((ext_vector_type(8))) short short8;
typedef __attribute__((ext_vector_type(4))) short short4b;
typedef __attribute__((ext_vector_type(4))) float f32x4;

union U32x2 { unsigned u[2]; short4b s4; };

__device__ __forceinline__ ushort f2bf(float f) {
  union { __hip_bfloat16 b; ushort u; } cv; cv.b = __float2bfloat16(f); return cv.u;
}
__device__ __forceinline__ float bf2f(ushort u) {
  unsigned x = ((unsigned)u) << 16; float f; __builtin_memcpy(&f, &x, 4); return f;
}
// compiler-friendly pack (clang fuses to v_cvt_pk_bf16_f32)
__device__ __forceinline__ unsigned pack2(float a, float b) {
  return (unsigned)f2bf(a) | ((unsigned)f2bf(b) << 16);
}

// async global->LDS, 16B per lane (dest = wave-uniform base + lane*16)
__device__ __forceinline__ void gl16(const ushort* g, ushort* l) {
  typedef const __attribute__((address_space(1))) unsigned GU;
  typedef __attribute__((address_space(3))) unsigned LU;
  __builtin_amdgcn_global_load_lds((GU*)g, (LU*)l, 16, 0, 0);
}

// 16x16x16 bf16 MFMA (K=16, A/B k-granule = lg*4+i) — builtin-name guarded.
__device__ __forceinline__ f32x4 mfma16(short4b a, short4b b, f32x4 c) {
#if __has_builtin(__builtin_amdgcn_mfma_f32_16x16x16bf16_1k)
  return __builtin_amdgcn_mfma_f32_16x16x16bf16_1k(a, b, c, 0, 0, 0);
#elif __has_builtin(__builtin_amdgcn_mfma_f32_16x16x16_bf16)
  return __builtin_amdgcn_mfma_f32_16x16x16_bf16(a, b, c, 0, 0, 0);
#else
  asm("v_mfma_f32_16x16x16_bf16 %0, %1, %2, %0" : "+v"(c) : "v"(a), "v"(b));
  return c;
#endif
}

// ---------------- fused prep: x-convert | 4 weight-converts | rope tables -----
// flat bid partition: [0,6144) x | [6144,8448) weights | [8448,8960) rope.
__global__ void k_prep(const float* __restrict__ x,
                       const float* __restrict__ w0, const float* __restrict__ w1,
                       const float* __restrict__ w2, const float* __restrict__ w3,
                       ushort* __restrict__ xb,
                       ushort* __restrict__ o0, ushort* __restrict__ o1,
                       ushort* __restrict__ o2, ushort* __restrict__ o3,
                       float* __restrict__ ctab, float* __restrict__ stab) {
  const int bid = blockIdx.x;
  if (bid < 6144) {                         // x: BT_*C_/4 = 1,572,864 float4
    const int i = bid * 256 + threadIdx.x;
    const float4 v = ((const float4*)x)[i];
    ushort4 o;
    o.x = f2bf(v.x); o.y = f2bf(v.y); o.z = f2bf(v.z); o.w = f2bf(v.w);
    ((ushort4*)xb)[i] = o;
  } else if (bid < 8448) {                  // weights: 4 x 576 blocks
    const int r = bid - 6144;
    const int sel = r / 576;
    const int i = (r % 576) * 256 + threadIdx.x;
    const float* in = sel == 0 ? w0 : (sel == 1 ? w1 : (sel == 2 ? w2 : w3));
    ushort* out = sel == 0 ? o0 : (sel == 1 ? o1 : (sel == 2 ? o2 : o3));
    const float4 v = ((const float4*)in)[i];
    ushort4 o;
    o.x = f2bf(v.x); o.y = f2bf(v.y); o.z = f2bf(v.z); o.w = f2bf(v.w);
    ((ushort4*)out)[i] = o;
  } else {                                  // rope tables: T_*32 = 131,072
    const int i = (bid - 8448) * 256 + threadIdx.x;
    const int t = i >> 5, p = i & 31;
    float inv = 1.0f / powf(10000.0f, (2.0f * (float)p) / 64.0f);
    float a = (float)t * inv;
    ctab[i] = cosf(a); stab[i] = sinf(a);
  }
}

// ---------------- QKV projection GEMM (RoPE fused into q/k epilogue) ----------
// NEW: BM=64 x BN=128 -> grid (128, 18) = 2304 blocks = exactly 9/CU uniform
// (was (64,18) = 1152 = 4.5/CU imbalanced). 24 KB LDS -> 6 co-resident.
// Wave w covers all 64 rows x cols [w*32, +32): acc[4][2]. Staging/frag-read
// geometry identical to the proven proj kernel (rule-21 swizzle).
__global__ __launch_bounds__(256) void k_qkv_gemm(
    const ushort* __restrict__ xb, const ushort* __restrict__ wq,
    const ushort* __restrict__ wk, const ushort* __restrict__ wv,
    const float* __restrict__ bq, const float* __restrict__ bk, const float* __restrict__ bv,
    const float* __restrict__ ctab, const float* __restrict__ stab,
    ushort* __restrict__ qo, ushort* __restrict__ ko, ushort* __restrict__ vo) {
  __shared__ __align__(16) ushort As[64 * 64];
  __shared__ __align__(16) ushort Bs[128 * 64];
  const int tid = threadIdx.x, l = tid & 63, w = tid >> 6;
  const int lr = l & 15, lg = l >> 4;
  const int m0 = blockIdx.x * 64;
  const int n0g = blockIdx.y * 128;
  const int proj = n0g / 768;
  const int n0 = n0g % 768;
  const ushort* wsrc = proj == 0 ? wq : (proj == 1 ? wk : wv);
  const int wc = w * 32;

  f32x4 acc[4][2];
  #pragma unroll
  for (int a = 0; a < 4; ++a)
    #pragma unroll
    for (int b = 0; b < 2; ++b) acc[a][b] = (f32x4){0.f, 0.f, 0.f, 0.f};

  const int srowA = w * 16 + (l >> 3);
  const int scgA = ((l & 7) ^ (srowA & 7)) * 8;
  const int srowB = w * 32 + (l >> 3);
  const int scgB = ((l & 7) ^ (srowB & 7)) * 8;

  for (int k0 = 0; k0 < 768; k0 += 64) {
    #pragma unroll
    for (int i = 0; i < 2; ++i) {
      const int row = srowA + i * 8;
      gl16(xb + (size_t)(m0 + row) * 768 + k0 + scgA, &As[(w * 16 + i * 8) * 64]);
    }
    #pragma unroll
    for (int i = 0; i < 4; ++i) {
      const int row = srowB + i * 8;
      gl16(wsrc + (size_t)(n0 + row) * 768 + k0 + scgB, &Bs[(w * 32 + i * 8) * 64]);
    }
    __syncthreads();
    #pragma unroll
    for (int kk = 0; kk < 2; ++kk) {
      short8 af[4], bf[2];
      #pragma unroll
      for (int mi = 0; mi < 4; ++mi) {
        const int row = mi * 16 + lr;
        af[mi] = *(const short8*)&As[row * 64 + (((kk * 4 + lg) ^ (row & 7)) * 8)];
      }
      #pragma unroll
      for (int ni = 0; ni < 2; ++ni) {
        const int row = wc + ni * 16 + lr;
        bf[ni] = *(const short8*)&Bs[row * 64 + (((kk * 4 + lg) ^ (row & 7)) * 8)];
      }
      #pragma unroll
      for (int mi = 0; mi < 4; ++mi)
        #pragma unroll
        for (int ni = 0; ni < 2; ++ni)
          acc[mi][ni] = __builtin_amdgcn_mfma_f32_16x16x32_bf16(af[mi], bf[ni], acc[mi][ni], 0, 0, 0);
    }
    __syncthreads();
  }

  const float* bias = proj == 0 ? bq : (proj == 1 ? bk : bv);
  if (proj == 2) {
    #pragma unroll
    for (int mi = 0; mi < 4; ++mi) {
      #pragma unroll
      for (int ni = 0; ni < 2; ++ni) {
        int colc = n0 + wc + ni * 16 + lr;
        float bb = bias[colc];
        int h = colc >> 6, d = colc & 63;
        int row0 = m0 + mi * 16 + lg * 4;
        int b = row0 >> 12, t0 = row0 & (T_ - 1);
        ushort4 pk;
        pk.x = f2bf(acc[mi][ni][0] + bb);
        pk.y = f2bf(acc[mi][ni][1] + bb);
        pk.z = f2bf(acc[mi][ni][2] + bb);
        pk.w = f2bf(acc[mi][ni][3] + bb);
        *(ushort4*)(vo + (((size_t)b * H_ + h) * 64 + d) * T_ + t0) = pk;
      }
    }
  } else {
    // fused RoPE epilogue: d-pair partner lives in adjacent lane (lr^1).
    ushort* dst = proj == 0 ? qo : ko;
    const float qs = proj == 0 ? 0.18033688011112042f : 1.0f;   // log2(e)/8
    #pragma unroll
    for (int mi = 0; mi < 4; ++mi) {
      #pragma unroll
      for (int ni = 0; ni < 2; ++ni) {
        int colc = n0 + wc + ni * 16 + lr;
        float bb = bias[colc];
        int h = colc >> 6, d = colc & 63;
        const int pidx = d >> 1;
        const bool evn = (d & 1) == 0;
        #pragma unroll
        for (int j = 0; j < 4; ++j) {
          int row = m0 + mi * 16 + lg * 4 + j;
          int b = row >> 12, t = row & (T_ - 1);
          float val = acc[mi][ni][j] + bb;          // biased (rope is post-bias)
          float prt = __shfl_xor(val, 1);           // partner d^1 (lane lr^1)
          float cc = ctab[(t << 5) + pidx];
          float ss = stab[(t << 5) + pidx];
          float ro = evn ? (val * cc - prt * ss) : (prt * ss + val * cc);
          dst[((((size_t)b * H_ + h) << 12) + t) * 64 + d] = f2bf(ro * qs);
        }
      }
    }
  }
}

// ---------------- output projection GEMM (f32 out) ----------------
// BM=64 x BN=128 -> grid (128, 6) = 768 = exactly 3/CU uniform. 24 KB LDS.
__global__ __launch_bounds__(256) void k_proj_gemm(
    const ushort* __restrict__ yb, const ushort* __restrict__ wp,
    const float* __restrict__ bp, float* __restrict__ out) {
  __shared__ __align__(16) ushort As[64 * 64];
  __shared__ __align__(16) ushort Bs[128 * 64];
  const int tid = threadIdx.x, l = tid & 63, w = tid >> 6;
  const int lr = l & 15, lg = l >> 4;
  const int m0 = blockIdx.x * 64;
  const int n0 = blockIdx.y * 128;
  const int wc = w * 32;

  f32x4 acc[4][2];
  #pragma unroll
  for (int a = 0; a < 4; ++a)
    #pragma unroll
    for (int b = 0; b < 2; ++b) acc[a][b] = (f32x4){0.f, 0.f, 0.f, 0.f};

  const int srowA = w * 16 + (l >> 3);
  const int scgA = ((l & 7) ^ (srowA & 7)) * 8;
  const int srowB = w * 32 + (l >> 3);
  const int scgB = ((l & 7) ^ (srowB & 7)) * 8;

  for (int k0 = 0; k0 < 768; k0 += 64) {
    #pragma unroll
    for (int i = 0; i < 2; ++i) {
      const int row = srowA + i * 8;
      gl16(yb + (size_t)(m0 + row) * 768 + k0 + scgA, &As[(w * 16 + i * 8) * 64]);
    }
    #pragma unroll
    for (int i = 0; i < 4; ++i) {
      const int row = srowB + i * 8;
      gl16(wp + (size_t)(n0 + row) * 768 + k0 + scgB, &Bs[(w * 32 + i * 8) * 64]);
    }
    __syncthreads();
    #pragma unroll
    for (int kk = 0; kk < 2; ++kk) {
      short8 af[4], bf[2];
      #pragma unroll
      for (int mi = 0; mi < 4; ++mi) {
        const int row = mi * 16 + lr;
        af[mi] = *(const short8*)&As[row * 64 + (((kk * 4 + lg) ^ (row & 7)) * 8)];
      }
      #pragma unroll
      for (int ni = 0; ni < 2; ++ni) {
        const int row = wc + ni * 16 + lr;
        bf[ni] = *(const short8*)&Bs[row * 64 + (((kk * 4 + lg) ^ (row & 7)) * 8)];
      }
      #pragma unroll
      for (int mi = 0; mi < 4; ++mi)
        #pragma unroll
        for (int ni = 0; ni < 2; ++ni)
          acc[mi][ni] = __builtin_amdgcn_mfma_f32_16x16x32_bf16(af[mi], bf[ni], acc[mi][ni], 0, 0, 0);
    }
    __syncthreads();
  }

  #pragma unroll
  for (int mi = 0; mi < 4; ++mi)
    #pragma unroll
    for (int ni = 0; ni < 2; ++ni) {
      int col = n0 + wc + ni * 16 + lr;
      float bb = bp[col];
      #pragma unroll
      for (int j = 0; j < 4; ++j) {
        int row = m0 + mi * 16 + lg * 4 + j;
        out[(size_t)row * 768 + col] = acc[mi][ni][j] + bb;
      }
    }
}

// ---------------- causal flash attention: UNIFORM 65-iter blocks --------------
// R17/R19-proven optimum VERBATIM (131 us): reg round-trip async-split staging,
// exponent-triggered rescale (no max tracking), MFMA denominator, setprio.
__global__ __launch_bounds__(256) void k_attn(
    const ushort* __restrict__ q, const ushort* __restrict__ k,
    const ushort* __restrict__ vt, ushort* __restrict__ y) {
  __shared__ __align__(16) ushort Ks[2][64 * 64];
  __shared__ __align__(16) ushort Vs[2][64 * 64];
  const int tid = threadIdx.x, l = tid & 63, w = tid >> 6;
  const int lr = l & 15, lg = l >> 4;
  const int p = blockIdx.x & 31;
  const int bh = blockIdx.x >> 5;
  const size_t kpl = (size_t)bh * T_ * 64;
  const size_t vpl = (size_t)bh * 64 * T_;
  const int b = bh / H_, h = bh % H_;
  const short4b ones4 = { (short)0x3F80, (short)0x3F80, (short)0x3F80, (short)0x3F80 };

  #pragma unroll 1
  for (int ph = 0; ph < 2; ++ph) {
    const int t = ph == 0 ? p : 63 - p;
    const int nt = t + 1;
    const int qrow = t * 64 + w * 16 + lr;

    // Q fragments (B operand of S^T = K·Q: col=q=lane&15, k-rows = d)
    short8 qf[2];
    #pragma unroll
    for (int kk = 0; kk < 2; ++kk)
      qf[kk] = *(const short8*)(q + kpl + (size_t)qrow * 64 + kk * 32 + lg * 8);

    f32x4 o[4];
    f32x4 lsa = (f32x4){0.f, 0.f, 0.f, 0.f};   // MFMA-accumulated denominator
    float mx = 0.0f;   // running shift (grows only via exponent rescale)
    #pragma unroll
    for (int c = 0; c < 4; ++c) o[c] = (f32x4){0.f, 0.f, 0.f, 0.f};

    __syncthreads();   // previous phase's LDS reads complete before re-staging
    // prologue: stage tile 0 into buf 0 (XOR-swizzled 16B slots)
    {
      #pragma unroll
      for (int i2 = 0; i2 < 2; ++i2) {
        const int r = w * 16 + i2 * 8 + (l >> 3);
        const int sl = (l & 7) ^ (r & 7);
        short8 s0 = *(const short8*)(k + kpl + (size_t)r * 64 + (l & 7) * 8);
        short8 v0 = *(const short8*)(vt + vpl + (size_t)r * T_ + (l & 7) * 8);
        *(short8*)&Ks[0][r * 64 + sl * 8] = s0;
        *(short8*)&Vs[0][r * 64 + sl * 8] = v0;
      }
    }

    int buf = 0;
    for (int kt = 0; kt < nt; ++kt) {
      __syncthreads();
      // async-split staging: issue next tile's global loads before compute
      short8 sk[2], sv[2];
      const bool pre = (kt + 1 < nt);
      if (pre) {
        #pragma unroll
        for (int i2 = 0; i2 < 2; ++i2) {
          const int r = w * 16 + i2 * 8 + (l >> 3);
          sk[i2] = *(const short8*)(k + kpl + (size_t)((kt + 1) * 64 + r) * 64 + (l & 7) * 8);
          sv[i2] = *(const short8*)(vt + vpl + (size_t)r * T_ + (kt + 1) * 64 + (l & 7) * 8);
        }
      }

      // ---- S^T = K·Q - mx (shift folded into MFMA C-init) ----
      const f32x4 zinit = (f32x4){-mx, -mx, -mx, -mx};
      f32x4 sT[4];
      __builtin_amdgcn_s_setprio(1);
      #pragma unroll
      for (int c = 0; c < 4; ++c) {
        short8 kf0 = *(const short8*)&Ks[buf][(c * 16 + lr) * 64 + ((lg) ^ (lr & 7)) * 8];
        short8 kf1 = *(const short8*)&Ks[buf][(c * 16 + lr) * 64 + ((4 + lg) ^ (lr & 7)) * 8];
        f32x4 z = zinit;
        z = __builtin_amdgcn_mfma_f32_16x16x32_bf16(kf0, qf[0], z, 0, 0, 0);
        z = __builtin_amdgcn_mfma_f32_16x16x32_bf16(kf1, qf[1], z, 0, 0, 0);
        sT[c] = z;
      }
      __builtin_amdgcn_s_setprio(0);

      // ---- causal mask on diagonal tile (S^T row=key, col=q) ----
      if (kt == t) {
        #pragma unroll
        for (int c = 0; c < 4; ++c)
          #pragma unroll
          for (int jj = 0; jj < 4; ++jj)
            if (kt * 64 + c * 16 + lg * 4 + jj > qrow) sT[c][jj] = -1e30f;
      }

      // ---- exponent-triggered rescale (no max tracking, no cross-lane) ----
      const unsigned lbits = __builtin_bit_cast(unsigned, lsa[0]);
      if (lbits > 0x4B800000u) {            // lsa > 2^24 (uint cmp, positive f32)
        const int e = (int)((lbits >> 23) & 0xFF) - 127;
        const float g = (float)e;
        const float corr = __builtin_bit_cast(float, (unsigned)((127 - e) << 23)); // 2^-e
        mx += g;
        lsa *= corr;
        #pragma unroll
        for (int c = 0; c < 4; ++c) o[c] *= corr;
        #pragma unroll
        for (int c = 0; c < 4; ++c)
          #pragma unroll
          for (int jj = 0; jj < 4; ++jj) sT[c][jj] -= g;
      }
      // common path: p = exp2(sT) directly — no max, no subtraction, no shfl
      U32x2 pb[4];
      #pragma unroll
      for (int c = 0; c < 4; ++c) {
        float p0 = exp2f(sT[c][0]);
        float p1 = exp2f(sT[c][1]);
        float p2 = exp2f(sT[c][2]);
        float p3 = exp2f(sT[c][3]);
        pb[c].u[0] = pack2(p0, p1); pb[c].u[1] = pack2(p2, p3);
      }

      // ---- O^T += V^T·P^T and lsa += 1^T·P^T via 16x16x16 (P in-lane) ----
      __builtin_amdgcn_s_setprio(1);
      #pragma unroll
      for (int ks = 0; ks < 4; ++ks) {
        lsa = mfma16(ones4, pb[ks].s4, lsa);    // denominator on the MFMA pipe
        #pragma unroll
        for (int c = 0; c < 4; ++c) {
          const int row = c * 16 + lr;
          const int sl = (2 * ks + (lg >> 1)) ^ (row & 7);
          short4b va = *(const short4b*)&Vs[buf][row * 64 + sl * 8 + (lg & 1) * 4];
          o[c] = mfma16(va, pb[ks].s4, o[c]);
        }
      }
      __builtin_amdgcn_s_setprio(0);

      if (pre) {
        #pragma unroll
        for (int i2 = 0; i2 < 2; ++i2) {
          const int r = w * 16 + i2 * 8 + (l >> 3);
          const int sl = (l & 7) ^ (r & 7);
          *(short8*)&Ks[buf ^ 1][r * 64 + sl * 8] = sk[i2];
          *(short8*)&Vs[buf ^ 1][r * 64 + sl * 8] = sv[i2];
        }
      }
      buf ^= 1;
    }

    // phase epilogue: normalize (lane-local; lsa rows all equal) + write y
    const float linv = 1.0f / lsa[0];
    const size_t base = ((size_t)b * T_ + qrow) * C_ + h * 64;
    #pragma unroll
    for (int c = 0; c < 4; ++c) {
      ushort4 pk;
      pk.x = f2bf(o[c][0] * linv);
      pk.y = f2bf(o[c][1] * linv);
      pk.z = f2bf(o[c][2] * linv);
      pk.w = f2bf(o[c][3] * linv);
      *(ushort4*)(y + base + c * 16 + lg * 4) = pk;
    }
  }
}

extern "C" void kernel_launch(void* const* d_in, const int* in_sizes, int n_in,
                              void* d_out, int out_size, void* d_ws, size_t ws_size,
                              hipStream_t stream) {
  const float* x  = (const float*)d_in[0];
  const float* Wq = (const float*)d_in[1];
  const float* bq = (const float*)d_in[2];
  const float* Wk = (const float*)d_in[3];
  const float* bk = (const float*)d_in[4];
  const float* Wv = (const float*)d_in[5];
  const float* bv = (const float*)d_in[6];
  const float* Wp = (const float*)d_in[7];
  const float* bp = (const float*)d_in[8];
  float* out = (float*)d_out;

  // ws: exact R3-proven footprint (~69 MB)
  char* p = (char*)d_ws;
  auto alloc = [&](size_t bytes) { char* r = p; p += (bytes + 255) & ~255ULL; return r; };
  ushort* xb  = (ushort*)alloc((size_t)BT_ * C_ * 2);
  ushort* wqb = (ushort*)alloc((size_t)C_ * C_ * 2);
  ushort* wkb = (ushort*)alloc((size_t)C_ * C_ * 2);
  ushort* wvb = (ushort*)alloc((size_t)C_ * C_ * 2);
  ushort* wpb = (ushort*)alloc((size_t)C_ * C_ * 2);
  ushort* qb  = (ushort*)alloc((size_t)BT_ * C_ * 2);
  ushort* kb  = (ushort*)alloc((size_t)BT_ * C_ * 2);
  ushort* vtb = (ushort*)alloc((size_t)BT_ * C_ * 2);   // V^T [B,H,64,T]
  ushort* yb  = (ushort*)alloc((size_t)BT_ * C_ * 2);
  float* ctab = (float*)alloc((size_t)T_ * 32 * 4);
  float* stab = (float*)alloc((size_t)T_ * 32 * 4);

  // fused prep: x-convert + 4 weight converts + rope tables in ONE launch
  k_prep<<<dim3(8960), 256, 0, stream>>>(x, Wq, Wk, Wv, Wp,
                                         xb, wqb, wkb, wvb, wpb, ctab, stab);

  // QKV projection with fused RoPE (q scaled by log2(e)/8 for exp2-domain softmax)
  k_qkv_gemm<<<dim3(BT_ / 64, 2304 / 128), 256, 0, stream>>>(
      xb, wqb, wkb, wvb, bq, bk, bv, ctab, stab, qb, kb, vtb);

  k_attn<<<dim3(768), 256, 0, stream>>>(qb, kb, vtb, yb);

  k_proj_gemm<<<dim3(BT_ / 64, C_ / 128), 256, 0, stream>>>(yb, wpb, bp, out);
}